// Round 4
// baseline (49.209 us; speedup 1.0000x reference)
//
#include <hip/hip_runtime.h>
#include <hip/hip_bf16.h>

#define NG 128
#define NT 16

// ws float layout:
//   gtab  [128][8]  : {betaT0..3, phi, phi*log(phi), 0, 0}          (1024 f)
//   mdemd [128][32] : md[16] then exp(md)[16]                       (4096 f)
//   lgtab [128][20] : gammaln(phi+k)-gammaln(1+k)-gammaln(phi)      (2560 f)
//   part  [64][nsp] : partial type-sums, layout [quarter*16+t][nsp]
#define GTAB_OFF 0
#define MDEMD_OFF 1024
#define LGTAB_OFF 5120
#define PART_OFF 8192
#define LN2 0.6931471805599453f
#define L2E 1.4426950408889634f
#define EXP2F(x) __builtin_amdgcn_exp2f(x)

__global__ void setup_kernel(const float* __restrict__ delta,
                             const float* __restrict__ beta,
                             const float* __restrict__ phi,
                             const float* __restrict__ mo,
                             float* __restrict__ ws,
                             float* __restrict__ out) {
    int g = threadIdx.x;
    if (g == 0) out[0] = 0.0f;   // deterministic re-init every call
    if (g >= NG) return;
    float* gtab  = ws + GTAB_OFF;
    float* mdemd = ws + MDEMD_OFF;
    float* lgtab = ws + LGTAB_OFF;

    float ph = phi[g];
    ph = fminf(fmaxf(ph, 1.0f), 100.0f);
    float lphi = logf(ph);
    gtab[g * 8 + 0] = beta[0 * NG + g];
    gtab[g * 8 + 1] = beta[1 * NG + g];
    gtab[g * 8 + 2] = beta[2 * NG + g];
    gtab[g * 8 + 3] = beta[3 * NG + g];
    gtab[g * 8 + 4] = ph;
    gtab[g * 8 + 5] = ph * lphi;
    gtab[g * 8 + 6] = 0.0f;
    gtab[g * 8 + 7] = 0.0f;

    for (int t = 0; t < NT; ++t) {
        float md = mo[g * NT + t] * delta[g * NT + t];
        mdemd[g * 32 + t]      = md;
        mdemd[g * 32 + 16 + t] = expf(md);
    }

    double accn = 0.0, lf = 0.0;
    lgtab[g * 20 + 0] = 0.0f;
    for (int k = 1; k < 20; ++k) {
        accn += log((double)ph + (double)(k - 1));
        if (k >= 2) lf += log((double)k);
        lgtab[g * 20 + k] = (float)(accn - lf);
    }
}

// Phase 1: block = 64 samples x 32 genes (one quarter). 4 waves, 8 genes each.
// All per-gene tables come in through scalar loads (wave-uniform indices);
// only the per-lane lgtab[k] gather uses LDS.
__global__ __launch_bounds__(256, 4) void nb_phase1(const float* __restrict__ expr,
                                                    const float* __restrict__ cov,
                                                    const float* __restrict__ sfv,
                                                    const float* __restrict__ ws,
                                                    float* __restrict__ part_out,
                                                    int ns, int nsp) {
    __shared__ float s_lg[640];
    __shared__ float part[4][64][17];

    const int tid = threadIdx.x;
    const int tile = blockIdx.x >> 2;
    const int quarter = blockIdx.x & 3;

    if (tid < 160)
        *(float4*)&s_lg[tid * 4] = *(const float4*)(ws + LGTAB_OFF + quarter * 640 + tid * 4);
    __syncthreads();

    const int lane = tid & 63;
    const int q = __builtin_amdgcn_readfirstlane(tid >> 6);  // wave-uniform
    const int s = tile * 64 + lane;
    const bool valid = (s < ns);

    float acc[NT];
#pragma unroll
    for (int t = 0; t < NT; ++t) acc[t] = 0.0f;
    float hacc = 0.0f;

    float4 cv = make_float4(0.f, 0.f, 0.f, 0.f);
    float sf = 1.0f;
    if (valid) {
        cv = *reinterpret_cast<const float4*>(cov + (size_t)s * 4);
        sf = sfv[s];
    }
    const float lsf  = __logf(sf);        // ln(sf)
    const float lsf2 = lsf * L2E;         // log2(sf)

    const int gbase = quarter * 32 + q * 8;   // uniform gene base for this wave
    float kbuf[8] = {0, 0, 0, 0, 0, 0, 0, 0};
    if (valid) {
        float4 k0 = *reinterpret_cast<const float4*>(expr + (size_t)s * NG + gbase);
        float4 k1 = *reinterpret_cast<const float4*>(expr + (size_t)s * NG + gbase + 4);
        kbuf[0] = k0.x; kbuf[1] = k0.y; kbuf[2] = k0.z; kbuf[3] = k0.w;
        kbuf[4] = k1.x; kbuf[5] = k1.y; kbuf[6] = k1.z; kbuf[7] = k1.w;
    }

#pragma unroll
    for (int jj = 0; jj < 8; ++jj) {
        const int g = gbase + jj;                          // uniform
        const float* __restrict__ gt = ws + GTAB_OFF + g * 8;
        const float* __restrict__ mp = ws + MDEMD_OFF + g * 32;
        const float b0 = gt[0], b1 = gt[1], b2 = gt[2], b3 = gt[3];
        const float ph = gt[4], plp = gt[5];

        float e = fmaf(b3, cv.w, fmaf(b2, cv.z, fmaf(b1, cv.y, b0 * cv.x)));
        float c = EXP2F(fmaf(e, L2E, lsf2));               // sf * exp(e)
        float kf = kbuf[jj];
        int ki = (int)kf;
        float lg = s_lg[(q * 8 + jj) * 20 + ki];           // per-lane gather
        hacc += fmaf(kf, lsf + e, lg + plp);               // type-independent
        float nkp2 = -(kf + ph) * LN2;
#pragma unroll
        for (int t = 0; t < NT; ++t) {
            const float md  = mp[t];                       // scalar (SGPR)
            const float emd = mp[16 + t];                  // scalar (SGPR)
            float v = fmaf(c, emd, ph);                    // mu + phi
            acc[t] = fmaf(nkp2, __log2f(v), fmaf(kf, md, acc[t]));
        }
    }
#pragma unroll
    for (int t = 0; t < NT; ++t) acc[t] += hacc;

#pragma unroll
    for (int t = 0; t < NT; ++t) part[q][lane][t] = acc[t];
    __syncthreads();

    // wave q combines and stores types [q*4, q*4+4), coalesced b32 per type row
    const int t0 = q * 4;
#pragma unroll
    for (int dt = 0; dt < 4; ++dt) {
        int t = t0 + dt;
        float v = part[0][lane][t] + part[1][lane][t] + part[2][lane][t] + part[3][lane][t];
        part_out[(size_t)(quarter * NT + t) * nsp + tile * 64 + lane] = v;
    }
}

// Phase 2: per-sample combine of 4 quarter-partials + logsumexp + grand sum
__global__ __launch_bounds__(256) void nb_phase2(const float* __restrict__ part_in,
                                                 float* __restrict__ out,
                                                 int ns, int nsp) {
    const int s = blockIdx.x * 256 + threadIdx.x;
    float lp = 0.0f;
    if (s < ns) {
        float tot[NT];
#pragma unroll
        for (int t = 0; t < NT; ++t) tot[t] = 0.0f;
#pragma unroll
        for (int qt = 0; qt < 4; ++qt) {
#pragma unroll
            for (int t = 0; t < NT; ++t)
                tot[t] += part_in[(size_t)(qt * NT + t) * nsp + s];
        }
        float m = tot[0];
#pragma unroll
        for (int t = 1; t < NT; ++t) m = fmaxf(m, tot[t]);
        float sum = 0.0f;
#pragma unroll
        for (int t = 0; t < NT; ++t) sum += __expf(tot[t] - m);
        lp = m + __logf(sum);
    }
#pragma unroll
    for (int off = 32; off > 0; off >>= 1) lp += __shfl_down(lp, off);
    __shared__ float r[4];
    if ((threadIdx.x & 63) == 0) r[threadIdx.x >> 6] = lp;
    __syncthreads();
    if (threadIdx.x == 0) atomicAdd(out, r[0] + r[1] + r[2] + r[3]);
}

// Fallback: single-phase kernel (round-1 proven) if ws can't hold partials
__global__ __launch_bounds__(256) void nb_single(const float* __restrict__ expr,
                                                 const float* __restrict__ cov,
                                                 const float* __restrict__ sfv,
                                                 const float* __restrict__ ws,
                                                 float* __restrict__ out,
                                                 int ns) {
    const float* __restrict__ lgtab = ws + LGTAB_OFF;
    const int lane = threadIdx.x & 63;
    const int q = __builtin_amdgcn_readfirstlane(threadIdx.x >> 6);
    const int s = blockIdx.x * 64 + lane;
    const bool valid = (s < ns);

    float acc[NT];
#pragma unroll
    for (int t = 0; t < NT; ++t) acc[t] = 0.0f;
    float hacc = 0.0f;

    float4 cv = make_float4(0.f, 0.f, 0.f, 0.f);
    float sf = 1.0f;
    if (valid) {
        cv = *reinterpret_cast<const float4*>(cov + (size_t)s * 4);
        sf = sfv[s];
    }
    const float lsf = __logf(sf);
    const float lsf2 = lsf * L2E;
    const int g0 = q * 32;

    for (int gg = 0; gg < 32; ++gg) {
        const int g = g0 + gg;
        const float* __restrict__ gt = ws + GTAB_OFF + g * 8;
        const float* __restrict__ mp = ws + MDEMD_OFF + g * 32;
        const float b0 = gt[0], b1 = gt[1], b2 = gt[2], b3 = gt[3];
        const float ph = gt[4], plp = gt[5];

        float e = fmaf(b3, cv.w, fmaf(b2, cv.z, fmaf(b1, cv.y, b0 * cv.x)));
        float c = EXP2F(fmaf(e, L2E, lsf2));
        float kf = valid ? expr[(size_t)s * NG + g] : 0.0f;
        int ki = (int)kf;
        float lg = lgtab[g * 20 + ki];
        hacc += fmaf(kf, lsf + e, lg + plp);
        float nkp2 = -(kf + ph) * LN2;
#pragma unroll
        for (int t = 0; t < NT; ++t) {
            float v = fmaf(c, mp[16 + t], ph);
            acc[t] = fmaf(nkp2, __log2f(v), fmaf(kf, mp[t], acc[t]));
        }
    }
#pragma unroll
    for (int t = 0; t < NT; ++t) acc[t] += hacc;

    __shared__ float part[4][64][17];
#pragma unroll
    for (int t = 0; t < NT; ++t) part[q][lane][t] = acc[t];
    __syncthreads();

    if (threadIdx.x < 64) {
        float tot[NT];
#pragma unroll
        for (int t = 0; t < NT; ++t)
            tot[t] = part[0][lane][t] + part[1][lane][t] + part[2][lane][t] + part[3][lane][t];
        float m = tot[0];
#pragma unroll
        for (int t = 1; t < NT; ++t) m = fmaxf(m, tot[t]);
        float sum = 0.0f;
#pragma unroll
        for (int t = 0; t < NT; ++t) sum += __expf(tot[t] - m);
        float lp = m + __logf(sum);
        if (!valid) lp = 0.0f;
#pragma unroll
        for (int off = 32; off > 0; off >>= 1) lp += __shfl_down(lp, off);
        if (lane == 0) atomicAdd(out, lp);
    }
}

extern "C" void kernel_launch(void* const* d_in, const int* in_sizes, int n_in,
                              void* d_out, int out_size, void* d_ws, size_t ws_size,
                              hipStream_t stream) {
    const float* delta = (const float*)d_in[0];
    const float* beta  = (const float*)d_in[1];
    const float* phi   = (const float*)d_in[2];
    const float* expr  = (const float*)d_in[3];
    const float* cov   = (const float*)d_in[4];
    const float* sf    = (const float*)d_in[5];
    const float* mo    = (const float*)d_in[6];
    float* out = (float*)d_out;
    float* ws  = (float*)d_ws;
    const int ns = in_sizes[5];

    setup_kernel<<<1, 128, 0, stream>>>(delta, beta, phi, mo, ws, out);

    const int tiles = (ns + 63) / 64;
    const int nsp = tiles * 64;
    const size_t need = ((size_t)PART_OFF + 64ull * (size_t)nsp) * 4ull;

    if (ws_size >= need) {
        float* part = ws + PART_OFF;
        nb_phase1<<<tiles * 4, 256, 0, stream>>>(expr, cov, sf, ws, part, ns, nsp);
        nb_phase2<<<(ns + 255) / 256, 256, 0, stream>>>(part, out, ns, nsp);
    } else {
        nb_single<<<tiles, 256, 0, stream>>>(expr, cov, sf, ws, out, ns);
    }
}

// Round 5
// 37.380 us; speedup vs baseline: 1.3164x; 1.3164x over previous
//
#include <hip/hip_runtime.h>
#include <hip/hip_bf16.h>

#define NG 128
#define NT 16

// ws float layout (all tables contiguous, 7680 floats total):
//   gtab  [128][8]  : {betaT0..3, phi, 0, 0, 0}                      (1024 f)
//   mdemd [128][16][2] : {md, exp(md)} interleaved                   (4096 f)
//   lgtab [128][20] : gammaln(phi+k)-gammaln(1+k)-gammaln(phi)+phi*ln(phi) (2560 f)
#define GTAB_OFF 0
#define MDEMD_OFF 1024
#define LGTAB_OFF 5120
#define TAB_FLOATS 7680
#define LN2 0.6931471805599453f
#define L2E 1.4426950408889634f
#define EXP2F(x) __builtin_amdgcn_exp2f(x)

__global__ void setup_kernel(const float* __restrict__ delta,
                             const float* __restrict__ beta,
                             const float* __restrict__ phi,
                             const float* __restrict__ mo,
                             float* __restrict__ ws,
                             float* __restrict__ out) {
    const int g = threadIdx.x;
    if (g == 0) out[0] = 0.0f;   // deterministic re-init every call
    if (g >= NG) return;

    // ln(k!) for k=0..19 (precomputed; float precision is ample: abs threshold ~1.9e6)
    const float lnfact[20] = {
        0.0f, 0.0f, 0.69314718f, 1.79175947f, 3.17805383f,
        4.78749174f, 6.57925121f, 8.52516132f, 10.60460286f, 12.80182744f,
        15.10441253f, 17.50230781f, 19.98721446f, 22.55216381f, 25.19122114f,
        27.89927134f, 30.67186007f, 33.50507341f, 36.39544517f, 39.33988415f};

    float* gtab  = ws + GTAB_OFF;
    float* mdemd = ws + MDEMD_OFF;
    float* lgtab = ws + LGTAB_OFF;

    float ph = fminf(fmaxf(phi[g], 1.0f), 100.0f);
    float plp = ph * __logf(ph);

    gtab[g * 8 + 0] = beta[0 * NG + g];
    gtab[g * 8 + 1] = beta[1 * NG + g];
    gtab[g * 8 + 2] = beta[2 * NG + g];
    gtab[g * 8 + 3] = beta[3 * NG + g];
    gtab[g * 8 + 4] = ph;
    gtab[g * 8 + 5] = 0.0f;
    gtab[g * 8 + 6] = 0.0f;
    gtab[g * 8 + 7] = 0.0f;

#pragma unroll
    for (int t = 0; t < NT; ++t) {
        float md = mo[g * NT + t] * delta[g * NT + t];
        mdemd[g * 32 + 2 * t]     = md;
        mdemd[g * 32 + 2 * t + 1] = __expf(md);
    }

    // lgtab[k] = sum_{j<k} log(phi+j) - ln(k!) + phi*ln(phi)   (plp folded in)
    float accn = 0.0f;
    lgtab[g * 20 + 0] = plp;
#pragma unroll
    for (int k = 1; k < 20; ++k) {
        accn += __logf(ph + (float)(k - 1));
        lgtab[g * 20 + k] = accn - lnfact[k] + plp;
    }
}

// Single-phase: block = 64 samples x all 128 genes. 4 waves, 32 genes each.
// Tables staged to LDS once; inner (g,t) body = 3 fma + 1 log2 + 1 ds_read_b64.
__global__ __launch_bounds__(256) void nb_main(const float* __restrict__ expr,
                                               const float* __restrict__ cov,
                                               const float* __restrict__ sfv,
                                               const float* __restrict__ ws,
                                               float* __restrict__ out,
                                               int ns) {
    __shared__ float s_tab[TAB_FLOATS];          // 30.7 KB
    __shared__ float red[2][64][17];             // 8.7 KB  -> total 39.4 KB -> 4 blocks/CU

    const int tid = threadIdx.x;
    // cooperative contiguous table stage: 1920 float4
#pragma unroll
    for (int i = 0; i < 8; ++i) {
        int idx = tid + i * 256;
        if (idx < TAB_FLOATS / 4)
            *(float4*)&s_tab[idx * 4] = *(const float4*)(ws + idx * 4);
    }
    __syncthreads();

    const float* __restrict__ s_gt = s_tab + GTAB_OFF;    // [128][8]
    const float* __restrict__ s_md = s_tab + MDEMD_OFF;   // [128][16][2]
    const float* __restrict__ s_lg = s_tab + LGTAB_OFF;   // [128][20]

    const int lane = tid & 63;
    const int q = __builtin_amdgcn_readfirstlane(tid >> 6);  // wave-uniform
    const int s = blockIdx.x * 64 + lane;
    const bool valid = (s < ns);

    float acc[NT];
#pragma unroll
    for (int t = 0; t < NT; ++t) acc[t] = 0.0f;
    float hacc = 0.0f;

    float4 cv = make_float4(0.f, 0.f, 0.f, 0.f);
    float sf = 1.0f;
    if (valid) {
        cv = *reinterpret_cast<const float4*>(cov + (size_t)s * 4);
        sf = sfv[s];
    }
    const float lsf  = __logf(sf);
    const float lsf2 = lsf * L2E;

    const int g0 = q * 32;   // wave-uniform gene strip

    for (int g4 = 0; g4 < 8; ++g4) {
        float4 kv = make_float4(0.f, 0.f, 0.f, 0.f);
        if (valid)
            kv = *reinterpret_cast<const float4*>(expr + (size_t)s * NG + g0 + g4 * 4);
        float kfv[4] = {kv.x, kv.y, kv.z, kv.w};
#pragma unroll
        for (int j = 0; j < 4; ++j) {
            const int g = g0 + g4 * 4 + j;
            const float b0 = s_gt[g * 8 + 0];
            const float b1 = s_gt[g * 8 + 1];
            const float b2 = s_gt[g * 8 + 2];
            const float b3 = s_gt[g * 8 + 3];
            const float ph = s_gt[g * 8 + 4];

            float e = fmaf(b3, cv.w, fmaf(b2, cv.z, fmaf(b1, cv.y, b0 * cv.x)));
            float c = EXP2F(fmaf(e, L2E, lsf2));           // sf * exp(e)
            float kf = kfv[j];
            float lg = s_lg[g * 20 + (int)kf];             // per-lane gather (incl. plp)
            hacc += fmaf(kf, lsf + e, lg);                 // type-independent
            float nkp2 = -(kf + ph) * LN2;
            const float* __restrict__ mp = s_md + g * 32;
#pragma unroll
            for (int t = 0; t < NT; ++t) {
                float md  = mp[2 * t];                     // ds_read_b64 broadcast
                float emd = mp[2 * t + 1];
                float v = fmaf(c, emd, ph);                // mu + phi
                acc[t] = fmaf(nkp2, __log2f(v), fmaf(kf, md, acc[t]));
            }
        }
    }
#pragma unroll
    for (int t = 0; t < NT; ++t) acc[t] += hacc;

    // tree reduction across the 4 waves through red[2][64][17]
    if (q & 1) {                 // waves 1,3 publish
#pragma unroll
        for (int t = 0; t < NT; ++t) red[q >> 1][lane][t] = acc[t];
    }
    __syncthreads();
    if (!(q & 1)) {              // waves 0,2 absorb
#pragma unroll
        for (int t = 0; t < NT; ++t) acc[t] += red[q >> 1][lane][t];
    }
    __syncthreads();
    if (q == 2) {                // wave 2 publishes its half-sum
#pragma unroll
        for (int t = 0; t < NT; ++t) red[1][lane][t] = acc[t];
    }
    __syncthreads();
    if (q == 0) {                // wave 0 finishes: logsumexp + block sum
        float tot[NT];
        float m = -1e30f;
#pragma unroll
        for (int t = 0; t < NT; ++t) {
            tot[t] = acc[t] + red[1][lane][t];
            m = fmaxf(m, tot[t]);
        }
        float sum = 0.0f;
#pragma unroll
        for (int t = 0; t < NT; ++t) sum += __expf(tot[t] - m);
        float lp = m + __logf(sum);
        if (!valid) lp = 0.0f;
#pragma unroll
        for (int off = 32; off > 0; off >>= 1) lp += __shfl_down(lp, off);
        if (lane == 0) atomicAdd(out, lp);
    }
}

extern "C" void kernel_launch(void* const* d_in, const int* in_sizes, int n_in,
                              void* d_out, int out_size, void* d_ws, size_t ws_size,
                              hipStream_t stream) {
    const float* delta = (const float*)d_in[0];
    const float* beta  = (const float*)d_in[1];
    const float* phi   = (const float*)d_in[2];
    const float* expr  = (const float*)d_in[3];
    const float* cov   = (const float*)d_in[4];
    const float* sf    = (const float*)d_in[5];
    const float* mo    = (const float*)d_in[6];
    float* out = (float*)d_out;
    float* ws  = (float*)d_ws;
    const int ns = in_sizes[5];

    setup_kernel<<<1, 128, 0, stream>>>(delta, beta, phi, mo, ws, out);

    const int tiles = (ns + 63) / 64;
    nb_main<<<tiles, 256, 0, stream>>>(expr, cov, sf, ws, out, ns);
}

// Round 6
// 35.712 us; speedup vs baseline: 1.3780x; 1.0467x over previous
//
#include <hip/hip_runtime.h>
#include <hip/hip_bf16.h>

#define NG 128
#define NT 16

// ws float layout (all tables contiguous, 7680 floats total):
//   gtab  [128][8]  : {betaT0..3, phi, 0, 0, 0}                      (1024 f)
//   mdemd [128][16][2] : {md, exp(md)} interleaved                   (4096 f)
//   lgtab [128][20] : gammaln(phi+k)-gammaln(1+k)-gammaln(phi)+phi*ln(phi) (2560 f)
#define GTAB_OFF 0
#define MDEMD_OFF 1024
#define LGTAB_OFF 5120
#define TAB_FLOATS 7680
#define LN2 0.6931471805599453f
#define L2E 1.4426950408889634f
#define EXP2F(x) __builtin_amdgcn_exp2f(x)

__global__ void setup_kernel(const float* __restrict__ delta,
                             const float* __restrict__ beta,
                             const float* __restrict__ phi,
                             const float* __restrict__ mo,
                             float* __restrict__ ws,
                             float* __restrict__ out) {
    const int g = threadIdx.x;
    if (g == 0) out[0] = 0.0f;   // deterministic re-init every call
    if (g >= NG) return;

    // ln(k!) for k=0..19 (float precision ample: abs threshold ~1.9e6)
    const float lnfact[20] = {
        0.0f, 0.0f, 0.69314718f, 1.79175947f, 3.17805383f,
        4.78749174f, 6.57925121f, 8.52516132f, 10.60460286f, 12.80182744f,
        15.10441253f, 17.50230781f, 19.98721446f, 22.55216381f, 25.19122114f,
        27.89927134f, 30.67186007f, 33.50507341f, 36.39544517f, 39.33988415f};

    float* gtab  = ws + GTAB_OFF;
    float* mdemd = ws + MDEMD_OFF;
    float* lgtab = ws + LGTAB_OFF;

    float ph = fminf(fmaxf(phi[g], 1.0f), 100.0f);
    float plp = ph * __logf(ph);

    gtab[g * 8 + 0] = beta[0 * NG + g];
    gtab[g * 8 + 1] = beta[1 * NG + g];
    gtab[g * 8 + 2] = beta[2 * NG + g];
    gtab[g * 8 + 3] = beta[3 * NG + g];
    gtab[g * 8 + 4] = ph;
    gtab[g * 8 + 5] = 0.0f;
    gtab[g * 8 + 6] = 0.0f;
    gtab[g * 8 + 7] = 0.0f;

#pragma unroll
    for (int t = 0; t < NT; ++t) {
        float md = mo[g * NT + t] * delta[g * NT + t];
        mdemd[g * 32 + 2 * t]     = md;
        mdemd[g * 32 + 2 * t + 1] = __expf(md);
    }

    // lgtab[k] = sum_{j<k} log(phi+j) - ln(k!) + phi*ln(phi)
    float accn = 0.0f;
    lgtab[g * 20 + 0] = plp;
#pragma unroll
    for (int k = 1; k < 20; ++k) {
        accn += __logf(ph + (float)(k - 1));
        lgtab[g * 20 + k] = accn - lnfact[k] + plp;
    }
}

// Single-phase: block = 64 samples x 128 genes, 8 waves x 16 genes each.
// Tables in LDS (30.7 KB); reduction buffer ALIASES the table space after
// the main loop (tables dead by then) so LDS stays 30.7 KB -> >=4 blocks/CU.
__global__ __launch_bounds__(512) void nb_main(const float* __restrict__ expr,
                                               const float* __restrict__ cov,
                                               const float* __restrict__ sfv,
                                               const float* __restrict__ ws,
                                               float* __restrict__ out,
                                               int ns) {
    __shared__ float s_tab[TAB_FLOATS];          // 30.7 KB total LDS

    const int tid = threadIdx.x;
#pragma unroll
    for (int i = 0; i < 4; ++i) {
        int idx = tid + i * 512;
        if (idx < TAB_FLOATS / 4)
            *(float4*)&s_tab[idx * 4] = *(const float4*)(ws + idx * 4);
    }
    __syncthreads();

    const float* __restrict__ s_gt = s_tab + GTAB_OFF;    // [128][8]
    const float* __restrict__ s_md = s_tab + MDEMD_OFF;   // [128][16][2]
    const float* __restrict__ s_lg = s_tab + LGTAB_OFF;   // [128][20]

    const int lane = tid & 63;
    const int q = __builtin_amdgcn_readfirstlane(tid >> 6);  // wave id 0..7
    const int s = blockIdx.x * 64 + lane;
    const bool valid = (s < ns);

    float acc[NT];
#pragma unroll
    for (int t = 0; t < NT; ++t) acc[t] = 0.0f;
    float hacc = 0.0f;

    float4 cv = make_float4(0.f, 0.f, 0.f, 0.f);
    float sf = 1.0f;
    if (valid) {
        cv = *reinterpret_cast<const float4*>(cov + (size_t)s * 4);
        sf = sfv[s];
    }
    const float lsf  = __logf(sf);
    const float lsf2 = lsf * L2E;

    const int g0 = q * 16;   // wave-uniform gene strip (16 genes)

    for (int g4 = 0; g4 < 4; ++g4) {
        float4 kv = make_float4(0.f, 0.f, 0.f, 0.f);
        if (valid)
            kv = *reinterpret_cast<const float4*>(expr + (size_t)s * NG + g0 + g4 * 4);
        float kfv[4] = {kv.x, kv.y, kv.z, kv.w};
#pragma unroll
        for (int j = 0; j < 4; ++j) {
            const int g = g0 + g4 * 4 + j;
            const float b0 = s_gt[g * 8 + 0];
            const float b1 = s_gt[g * 8 + 1];
            const float b2 = s_gt[g * 8 + 2];
            const float b3 = s_gt[g * 8 + 3];
            const float ph = s_gt[g * 8 + 4];

            float e = fmaf(b3, cv.w, fmaf(b2, cv.z, fmaf(b1, cv.y, b0 * cv.x)));
            float c = EXP2F(fmaf(e, L2E, lsf2));           // sf * exp(e)
            float kf = kfv[j];
            float lg = s_lg[g * 20 + (int)kf];             // per-lane gather
            hacc += fmaf(kf, lsf + e, lg);                 // type-independent
            float nkp2 = -(kf + ph) * LN2;
            const float* __restrict__ mp = s_md + g * 32;
#pragma unroll
            for (int t = 0; t < NT; ++t) {
                float md  = mp[2 * t];                     // ds_read_b64 broadcast
                float emd = mp[2 * t + 1];
                float v = fmaf(c, emd, ph);                // mu + phi
                acc[t] = fmaf(nkp2, __log2f(v), fmaf(kf, md, acc[t]));
            }
        }
    }
#pragma unroll
    for (int t = 0; t < NT; ++t) acc[t] += hacc;

    // ---- tree reduction 8 -> 4 -> 2 -> 1 through LDS aliased onto s_tab ----
    float (*red)[64][17] = (float (*)[64][17])s_tab;   // 4*64*17 = 4352 <= 7680
    __syncthreads();                                   // tables dead from here

    if (q >= 4) {
#pragma unroll
        for (int t = 0; t < NT; ++t) red[q - 4][lane][t] = acc[t];
    }
    __syncthreads();
    if (q < 4) {
#pragma unroll
        for (int t = 0; t < NT; ++t) acc[t] += red[q][lane][t];
    }
    __syncthreads();
    if (q == 2 || q == 3) {
#pragma unroll
        for (int t = 0; t < NT; ++t) red[q - 2][lane][t] = acc[t];
    }
    __syncthreads();
    if (q < 2) {
#pragma unroll
        for (int t = 0; t < NT; ++t) acc[t] += red[q][lane][t];
    }
    __syncthreads();
    if (q == 1) {
#pragma unroll
        for (int t = 0; t < NT; ++t) red[0][lane][t] = acc[t];
    }
    __syncthreads();
    if (q == 0) {
        float m = -1e30f;
#pragma unroll
        for (int t = 0; t < NT; ++t) {
            acc[t] += red[0][lane][t];
            m = fmaxf(m, acc[t]);
        }
        float sum = 0.0f;
#pragma unroll
        for (int t = 0; t < NT; ++t) sum += __expf(acc[t] - m);
        float lp = m + __logf(sum);
        if (!valid) lp = 0.0f;
#pragma unroll
        for (int off = 32; off > 0; off >>= 1) lp += __shfl_down(lp, off);
        if (lane == 0) atomicAdd(out, lp);
    }
}

extern "C" void kernel_launch(void* const* d_in, const int* in_sizes, int n_in,
                              void* d_out, int out_size, void* d_ws, size_t ws_size,
                              hipStream_t stream) {
    const float* delta = (const float*)d_in[0];
    const float* beta  = (const float*)d_in[1];
    const float* phi   = (const float*)d_in[2];
    const float* expr  = (const float*)d_in[3];
    const float* cov   = (const float*)d_in[4];
    const float* sf    = (const float*)d_in[5];
    const float* mo    = (const float*)d_in[6];
    float* out = (float*)d_out;
    float* ws  = (float*)d_ws;
    const int ns = in_sizes[5];

    setup_kernel<<<1, 128, 0, stream>>>(delta, beta, phi, mo, ws, out);

    const int tiles = (ns + 63) / 64;
    nb_main<<<tiles, 512, 0, stream>>>(expr, cov, sf, ws, out, ns);
}